// Round 1
// baseline (320.231 us; speedup 1.0000x reference)
//
#include <hip/hip_runtime.h>

// MultiHeadSelfAttention: B=2, S=2048, E=768, H=12, D=64
// Pipeline: detect dtype -> ingest (bf16 conversions/transposes) -> QKV GEMM
//           -> flash attention -> output GEMM (+bias).
// All matmuls: v_mfma_f32_16x16x32_bf16, fp32 accumulation.

typedef __bf16 bf16_t;
typedef bf16_t bf16x8 __attribute__((ext_vector_type(8)));
typedef float f32x4 __attribute__((ext_vector_type(4)));

#define LOG2E 1.4426950408889634f

__device__ __forceinline__ float bf2f(unsigned short u) {
  union { unsigned int i; float f; } x;
  x.i = ((unsigned int)u) << 16;
  return x.f;
}

// ---------------------------------------------------------------- dtype probe
// If x is fp32, the low 16 bits of each word are random mantissa -> wild bf16
// exponents. If x is bf16, all values are ~N(0,1) -> exponent <= 0x82.
__global__ void k_detect(const unsigned short* __restrict__ x, int* __restrict__ flag) {
  int lane = threadIdx.x;
  int big = 0;
  for (int i = 0; i < 32; i++) {
    unsigned short u = x[lane + i * 64];
    int e = (u >> 7) & 0xFF;
    big |= (e > 0x88);  // |v| > ~1024
  }
  unsigned long long b = __ballot(big);
  if (lane == 0) *flag = (b == 0ULL) ? 1 : 0;  // 1 => inputs are bf16
}

// ---------------------------------------------------------------- x -> bf16
__global__ void k_ingest_x(const void* __restrict__ xsrc, const int* __restrict__ flag,
                           bf16_t* __restrict__ xb) {
  int i = blockIdx.x * 256 + threadIdx.x;   // each thread: 8 elements
  if (*flag) {
    ((uint4*)xb)[i] = ((const uint4*)xsrc)[i];
  } else {
    const float* xf = (const float*)xsrc + (size_t)i * 8;
    bf16x8 v;
#pragma unroll
    for (int j = 0; j < 8; j++) v[j] = (bf16_t)xf[j];
    *(bf16x8*)(xb + (size_t)i * 8) = v;
  }
}

// ------------------------------------------------- W (768x768) -> W^T bf16
__global__ void k_wtrans(const void* __restrict__ wsrc, const int* __restrict__ flag,
                         bf16_t* __restrict__ dst, int rowOff) {
  __shared__ float ts[32][33];
  const int kt = blockIdx.x, nt = blockIdx.y;
  const int c = threadIdx.x & 31, r0 = threadIdx.x >> 5;  // 8 rows per pass
  const int f = *flag;
#pragma unroll
  for (int i = 0; i < 4; i++) {
    int kr = kt * 32 + r0 + i * 8;
    float v;
    if (f) v = bf2f(((const unsigned short*)wsrc)[(size_t)kr * 768 + nt * 32 + c]);
    else   v = ((const float*)wsrc)[(size_t)kr * 768 + nt * 32 + c];
    ts[r0 + i * 8][c] = v;
  }
  __syncthreads();
#pragma unroll
  for (int i = 0; i < 4; i++) {
    int nr = nt * 32 + r0 + i * 8;
    dst[(size_t)(rowOff + nr) * 768 + kt * 32 + c] = (bf16_t)ts[c][r0 + i * 8];
  }
}

// ---------------------------------------------------------------- bo -> f32
__global__ void k_ingest_bo(const void* __restrict__ src, const int* __restrict__ flag,
                            float* __restrict__ dst) {
  int i = blockIdx.x * 256 + threadIdx.x;
  if (i < 768) {
    if (*flag) dst[i] = bf2f(((const unsigned short*)src)[i]);
    else       dst[i] = ((const float*)src)[i];
  }
}

// ------------------------------------------- mask nonzero flags per 128x128
__global__ void k_maskflags(const void* __restrict__ mask, const int* __restrict__ flag,
                            int* __restrict__ mflags) {
  __shared__ int s;
  const int qt = blockIdx.x, kt = blockIdx.y;
  const int f = *flag;
  if (threadIdx.x == 0) s = 0;
  __syncthreads();
  int nz = 0;
  for (int i = 0; i < 64; i++) {
    int lin = i * 256 + threadIdx.x;
    int r = lin >> 7, c = lin & 127;
    size_t idx = (size_t)(qt * 128 + r) * 2048 + kt * 128 + c;
    float v = f ? bf2f(((const unsigned short*)mask)[idx]) : ((const float*)mask)[idx];
    nz |= (v != 0.0f);
  }
  if (nz) s = 1;  // benign race, all write 1
  __syncthreads();
  if (threadIdx.x == 0) mflags[qt * 16 + kt] = s;
}

// --------------------------------------------------------------------- GEMM
// C[M x N] = A[M x 768] * B^T[N x 768], 128x128 tile, 256 thr (4 waves 2x2),
// each wave 64x64 via 4x4 grid of 16x16x32 MFMAs.
// MODE 0: N=2304 epilogue scatters Q[b,h,s,d], K[b,h,s,d], V^T[b,h,d,s] (bf16)
// MODE 1: N=768  epilogue adds bias, writes out (fp32 or bf16 per flag)
template <int MODE>
__global__ __launch_bounds__(256, 2) void k_gemm(
    const bf16_t* __restrict__ A, const bf16_t* __restrict__ Bm,
    bf16_t* __restrict__ Qd, bf16_t* __restrict__ Kd, bf16_t* __restrict__ Vt,
    float* __restrict__ outF, unsigned short* __restrict__ outH,
    const float* __restrict__ bias, const int* __restrict__ flag) {
  __shared__ __align__(16) bf16_t As[128][40];  // +8 pad keeps 16B align, spreads banks
  __shared__ __align__(16) bf16_t Bs[128][40];
  const int tid = threadIdx.x;
  const int n0 = blockIdx.x * 128, m0 = blockIdx.y * 128;
  const int r = tid >> 2, c8 = (tid & 3) << 3;
  const bf16_t* Ag = A + (size_t)(m0 + r) * 768 + c8;
  const bf16_t* Bg = Bm + (size_t)(n0 + r) * 768 + c8;
  const int wid = tid >> 6, lane = tid & 63;
  const int wm = (wid >> 1) << 6, wn = (wid & 1) << 6;
  const int lr = lane & 15, lk = (lane >> 4) << 3;

  f32x4 acc[4][4];
  const f32x4 z = {0.f, 0.f, 0.f, 0.f};
#pragma unroll
  for (int i = 0; i < 4; i++)
#pragma unroll
    for (int j = 0; j < 4; j++) acc[i][j] = z;

  for (int k0 = 0; k0 < 768; k0 += 32) {
    *(bf16x8*)&As[r][c8]      = *(const bf16x8*)(Ag + k0);
    *(bf16x8*)&As[r + 64][c8] = *(const bf16x8*)(Ag + (size_t)64 * 768 + k0);
    *(bf16x8*)&Bs[r][c8]      = *(const bf16x8*)(Bg + k0);
    *(bf16x8*)&Bs[r + 64][c8] = *(const bf16x8*)(Bg + (size_t)64 * 768 + k0);
    __syncthreads();
    bf16x8 af[4], bf_[4];
#pragma unroll
    for (int t = 0; t < 4; t++) af[t] = *(const bf16x8*)&As[wm + t * 16 + lr][lk];
#pragma unroll
    for (int t = 0; t < 4; t++) bf_[t] = *(const bf16x8*)&Bs[wn + t * 16 + lr][lk];
#pragma unroll
    for (int i = 0; i < 4; i++)
#pragma unroll
      for (int j = 0; j < 4; j++)
        acc[i][j] = __builtin_amdgcn_mfma_f32_16x16x32_bf16(af[i], bf_[j], acc[i][j], 0, 0, 0);
    __syncthreads();
  }

  const int g4 = (lane >> 4) << 2;
  if (MODE == 0) {
#pragma unroll
    for (int i = 0; i < 4; i++) {
#pragma unroll
      for (int j = 0; j < 4; j++) {
        const int nn = n0 + wn + j * 16 + lr;
        const int p = (nn >= 1536) ? 2 : (nn >= 768 ? 1 : 0);
        const int rc = nn - p * 768;
        const int h = rc >> 6, d = rc & 63;
#pragma unroll
        for (int reg = 0; reg < 4; reg++) {
          const int m = m0 + wm + i * 16 + g4 + reg;
          const int bb = m >> 11, s = m & 2047;
          const bf16_t v = (bf16_t)acc[i][j][reg];
          const size_t bh = (size_t)bb * 12 + h;
          if (p == 0)      Qd[(bh * 2048 + s) * 64 + d] = v;
          else if (p == 1) Kd[(bh * 2048 + s) * 64 + d] = v;
          else             Vt[(bh * 64 + d) * 2048 + s] = v;
        }
      }
    }
  } else {
    const int obf = *flag;
#pragma unroll
    for (int i = 0; i < 4; i++) {
#pragma unroll
      for (int j = 0; j < 4; j++) {
        const int nn = n0 + wn + j * 16 + lr;
        const float bv = bias[nn];
#pragma unroll
        for (int reg = 0; reg < 4; reg++) {
          const int m = m0 + wm + i * 16 + g4 + reg;
          const float v = acc[i][j][reg] + bv;
          if (obf) outH[(size_t)m * 768 + nn] = __builtin_bit_cast(unsigned short, (bf16_t)v);
          else     outF[(size_t)m * 768 + nn] = v;
        }
      }
    }
  }
}

// ----------------------------------------------------------- flash attention
// Block = (qtile of 128, head, batch); 4 waves, wave owns 32 q-rows.
// S-tile 128x128 via QK^T MFMA, online softmax, P through LDS (C->A layout),
// PV MFMA with V^T giving contiguous B-operand loads.
__global__ __launch_bounds__(256, 2) void k_flash(
    const bf16_t* __restrict__ Qd, const bf16_t* __restrict__ Kd,
    const bf16_t* __restrict__ Vt, const void* __restrict__ mask,
    const int* __restrict__ mflags, const int* __restrict__ flag,
    bf16_t* __restrict__ attn) {
  __shared__ __align__(16) bf16_t P[4][32][136];  // per-wave P, +8 pad
  const int qt = blockIdx.x, h = blockIdx.y, bb = blockIdx.z;
  const int tid = threadIdx.x, wid = tid >> 6, lane = tid & 63;
  const int lr = lane & 15, g = lane >> 4, lk = g << 3, g4 = g << 2;
  const int mbf = *flag;
  const size_t bh = (size_t)bb * 12 + h;
  const bf16_t* Qh = Qd + bh * 2048 * 64;
  const bf16_t* Kh = Kd + bh * 2048 * 64;
  const bf16_t* Vh = Vt + bh * 64 * 2048;
  const int q0 = qt * 128 + wid * 32;

  bf16x8 qf[2][2];
#pragma unroll
  for (int rt = 0; rt < 2; rt++)
#pragma unroll
    for (int c = 0; c < 2; c++)
      qf[rt][c] = *(const bf16x8*)&Qh[(size_t)(q0 + rt * 16 + lr) * 64 + c * 32 + lk];

  const f32x4 z = {0.f, 0.f, 0.f, 0.f};
  f32x4 o[2][4];
  float mrow[2][4], lrow[2][4];
#pragma unroll
  for (int rt = 0; rt < 2; rt++) {
#pragma unroll
    for (int dt = 0; dt < 4; dt++) o[rt][dt] = z;
#pragma unroll
    for (int reg = 0; reg < 4; reg++) { mrow[rt][reg] = -1e30f; lrow[rt][reg] = 0.f; }
  }

  for (int kt = 0; kt < 16; kt++) {
    // ---- S = Q K^T (scaled)
    f32x4 sv[2][8];
#pragma unroll
    for (int rt = 0; rt < 2; rt++)
#pragma unroll
      for (int ct = 0; ct < 8; ct++) sv[rt][ct] = z;
#pragma unroll
    for (int ct = 0; ct < 8; ct++) {
      bf16x8 kf0 = *(const bf16x8*)&Kh[(size_t)(kt * 128 + ct * 16 + lr) * 64 + lk];
      bf16x8 kf1 = *(const bf16x8*)&Kh[(size_t)(kt * 128 + ct * 16 + lr) * 64 + 32 + lk];
      sv[0][ct] = __builtin_amdgcn_mfma_f32_16x16x32_bf16(qf[0][0], kf0, sv[0][ct], 0, 0, 0);
      sv[0][ct] = __builtin_amdgcn_mfma_f32_16x16x32_bf16(qf[0][1], kf1, sv[0][ct], 0, 0, 0);
      sv[1][ct] = __builtin_amdgcn_mfma_f32_16x16x32_bf16(qf[1][0], kf0, sv[1][ct], 0, 0, 0);
      sv[1][ct] = __builtin_amdgcn_mfma_f32_16x16x32_bf16(qf[1][1], kf1, sv[1][ct], 0, 0, 0);
    }
#pragma unroll
    for (int rt = 0; rt < 2; rt++)
#pragma unroll
      for (int ct = 0; ct < 8; ct++) sv[rt][ct] *= 0.125f;  // 1/sqrt(64)

    if (mflags[qt * 16 + kt]) {  // additive mask (generic path; zero mask skips)
#pragma unroll
      for (int rt = 0; rt < 2; rt++)
#pragma unroll
        for (int ct = 0; ct < 8; ct++)
#pragma unroll
          for (int reg = 0; reg < 4; reg++) {
            size_t mi = (size_t)(qt * 128 + wid * 32 + rt * 16 + g4 + reg) * 2048 +
                        kt * 128 + ct * 16 + lr;
            float mv = mbf ? bf2f(((const unsigned short*)mask)[mi])
                           : ((const float*)mask)[mi];
            sv[rt][ct][reg] += -1e9f * mv;
          }
    }

    // ---- online softmax: row max / alpha
    float al[2][4];
#pragma unroll
    for (int rt = 0; rt < 2; rt++)
#pragma unroll
      for (int reg = 0; reg < 4; reg++) {
        float t = sv[rt][0][reg];
#pragma unroll
        for (int ct = 1; ct < 8; ct++) t = fmaxf(t, sv[rt][ct][reg]);
        t = fmaxf(t, __shfl_xor(t, 1));
        t = fmaxf(t, __shfl_xor(t, 2));
        t = fmaxf(t, __shfl_xor(t, 4));
        t = fmaxf(t, __shfl_xor(t, 8));
        float mn = fmaxf(mrow[rt][reg], t);
        al[rt][reg] = exp2f((mrow[rt][reg] - mn) * LOG2E);
        mrow[rt][reg] = mn;
      }

    // ---- P = exp(S - m), row sums, store P to LDS in C-layout
#pragma unroll
    for (int rt = 0; rt < 2; rt++) {
      float rs[4] = {0.f, 0.f, 0.f, 0.f};
#pragma unroll
      for (int ct = 0; ct < 8; ct++)
#pragma unroll
        for (int reg = 0; reg < 4; reg++) {
          float pv = exp2f((sv[rt][ct][reg] - mrow[rt][reg]) * LOG2E);
          rs[reg] += pv;
          P[wid][rt * 16 + g4 + reg][ct * 16 + lr] = (bf16_t)pv;
        }
#pragma unroll
      for (int reg = 0; reg < 4; reg++) {
        float t = rs[reg];
        t += __shfl_xor(t, 1);
        t += __shfl_xor(t, 2);
        t += __shfl_xor(t, 4);
        t += __shfl_xor(t, 8);
        lrow[rt][reg] = lrow[rt][reg] * al[rt][reg] + t;
      }
    }

    // ---- rescale O, then O += P V  (P read back in A-layout; same wave, no barrier)
#pragma unroll
    for (int rt = 0; rt < 2; rt++)
#pragma unroll
      for (int dt = 0; dt < 4; dt++)
#pragma unroll
        for (int reg = 0; reg < 4; reg++) o[rt][dt][reg] *= al[rt][reg];

    bf16x8 pf[2][4];
#pragma unroll
    for (int rt = 0; rt < 2; rt++)
#pragma unroll
      for (int c = 0; c < 4; c++)
        pf[rt][c] = *(const bf16x8*)&P[wid][rt * 16 + lr][c * 32 + lk];
#pragma unroll
    for (int dt = 0; dt < 4; dt++) {
#pragma unroll
      for (int c = 0; c < 4; c++) {
        bf16x8 vf = *(const bf16x8*)&Vh[(size_t)(dt * 16 + lr) * 2048 + kt * 128 + c * 32 + lk];
        o[0][dt] = __builtin_amdgcn_mfma_f32_16x16x32_bf16(pf[0][c], vf, o[0][dt], 0, 0, 0);
        o[1][dt] = __builtin_amdgcn_mfma_f32_16x16x32_bf16(pf[1][c], vf, o[1][dt], 0, 0, 0);
      }
    }
  }

  // ---- normalize, store attn in [b*S + s][h*64 + d] (concat-heads) layout
#pragma unroll
  for (int rt = 0; rt < 2; rt++) {
    float inv[4];
#pragma unroll
    for (int reg = 0; reg < 4; reg++) inv[reg] = 1.0f / lrow[rt][reg];
#pragma unroll
    for (int dt = 0; dt < 4; dt++)
#pragma unroll
      for (int reg = 0; reg < 4; reg++) {
        float v = o[rt][dt][reg] * inv[reg];
        attn[(size_t)((size_t)bb * 2048 + q0 + rt * 16 + g4 + reg) * 768 +
             h * 64 + dt * 16 + lr] = (bf16_t)v;
      }
  }
}

// -------------------------------------------------------------------- launch
extern "C" void kernel_launch(void* const* d_in, const int* in_sizes, int n_in,
                              void* d_out, int out_size, void* d_ws, size_t ws_size,
                              hipStream_t stream) {
  (void)in_sizes; (void)n_in; (void)out_size; (void)ws_size;
  const void* x    = d_in[0];
  const void* mask = d_in[1];
  const void* Wq   = d_in[2];
  const void* Wk   = d_in[3];
  const void* Wv   = d_in[4];
  const void* Wo   = d_in[5];
  const void* bo   = d_in[6];

  char* w = (char*)d_ws;
  size_t off = 0;
  auto take = [&](size_t b) -> void* {
    void* p = w + off;
    off = (off + b + 255) & ~(size_t)255;
    return p;
  };
  int*    flag   = (int*)take(4);
  int*    mflags = (int*)take(256 * 4);
  float*  boF    = (float*)take(768 * 4);
  bf16_t* wqkvT  = (bf16_t*)take((size_t)2304 * 768 * 2);
  bf16_t* woT    = (bf16_t*)take((size_t)768 * 768 * 2);
  bf16_t* xb     = (bf16_t*)take((size_t)4096 * 768 * 2);
  bf16_t* Qd     = (bf16_t*)take((size_t)3145728 * 2);
  bf16_t* Kd     = (bf16_t*)take((size_t)3145728 * 2);
  bf16_t* Vt     = (bf16_t*)take((size_t)3145728 * 2);
  bf16_t* attn   = xb;  // alias: xb dead after GEMM1; flash writes attn after

  k_detect<<<1, 64, 0, stream>>>((const unsigned short*)x, flag);
  k_ingest_x<<<1536, 256, 0, stream>>>(x, flag, xb);
  k_wtrans<<<dim3(24, 24), 256, 0, stream>>>(Wq, flag, wqkvT, 0);
  k_wtrans<<<dim3(24, 24), 256, 0, stream>>>(Wk, flag, wqkvT, 768);
  k_wtrans<<<dim3(24, 24), 256, 0, stream>>>(Wv, flag, wqkvT, 1536);
  k_wtrans<<<dim3(24, 24), 256, 0, stream>>>(Wo, flag, woT, 0);
  k_ingest_bo<<<3, 256, 0, stream>>>(bo, flag, boF);
  k_maskflags<<<dim3(16, 16), 256, 0, stream>>>(mask, flag, mflags);
  k_gemm<0><<<dim3(18, 32), 256, 0, stream>>>(xb, wqkvT, Qd, Kd, Vt,
                                              nullptr, nullptr, nullptr, flag);
  k_flash<<<dim3(16, 12, 2), 256, 0, stream>>>(Qd, Kd, Vt, mask, mflags, flag, attn);
  k_gemm<1><<<dim3(6, 32), 256, 0, stream>>>(attn, woT, nullptr, nullptr, nullptr,
                                             (float*)d_out, (unsigned short*)d_out,
                                             boF, flag);
}